// Round 11
// baseline (466.400 us; speedup 1.0000x reference)
//
#include <hip/hip_runtime.h>
#include <hip/hip_bf16.h>
#include <math.h>

typedef __hip_bfloat16 bf16;
typedef __bf16 bf16x8 __attribute__((ext_vector_type(8)));
typedef float floatx4 __attribute__((ext_vector_type(4)));

__device__ __forceinline__ unsigned short f2bu(float f) {
    bf16 b = __float2bfloat16(f);
    return __builtin_bit_cast(unsigned short, b);
}
__device__ __forceinline__ float bu2f(unsigned short u) {
    return __uint_as_float(((unsigned)u) << 16);
}

// load PF bf16 features (packed) as floats
template<int PF>
__device__ __forceinline__ void ldbf(const bf16* p, float* v) {
    if constexpr (PF == 1) {
        unsigned short u = *reinterpret_cast<const unsigned short*>(p);
        v[0] = __uint_as_float(((unsigned)u) << 16);
    } else {
        unsigned u = *reinterpret_cast<const unsigned*>(p);
        v[0] = __uint_as_float(u << 16);
        v[1] = __uint_as_float(u & 0xffff0000u);
    }
}

// ====== MFMA GEMM + fused alpha: C[N,16H] = X[N,128] @ W[128,16H] ===========
// K=128 in LDS, one staging phase. Fragment layouts (m89/m91-verified):
// A[m=lane&15][k=quad*8+j], B[k=quad*8+j][n=lane&15], D[row=quad*4+reg][col=lane&15].
// Epilogue: D repacked to LDS -> coalesced bf16 store + per-row alpha dot.
template<typename XT, int H>
__global__ __launch_bounds__(256) void gemm_mfma(
    const XT* __restrict__ X, const float* __restrict__ W,
    const float* __restrict__ a_src, const float* __restrict__ a_dst,
    bf16* __restrict__ Hout, float* __restrict__ asrc, float* __restrict__ adst,
    int N)
{
    constexpr int M = H * 16;
    constexpr int KP = 136;              // padded k-stride (bf16 elems)
    constexpr int NT = M / 16;           // 16-col tiles per wave
    constexpr int HPQ = H / 4;           // heads per quarter-thread
    __shared__ __align__(16) unsigned short Wt[M * KP];   // W^T: [n][k]
    __shared__ __align__(16) unsigned short As[64 * KP];  // A: [m][k]; reused for D
    __shared__ float As_s[M], Ad_s[M];
    int tid = threadIdx.x;
    int r0 = blockIdx.x * 64;

    for (int i = tid; i < M; i += 256) { As_s[i] = a_src[i]; Ad_s[i] = a_dst[i]; }
    // stage W^T (bf16): global W[k][m] row-major, coalesced read
    for (int idx = tid; idx < 128 * M; idx += 256) {
        int k = idx / M, m = idx % M;
        Wt[m * KP + k] = f2bu(W[idx]);
    }
    // stage A tile (64 rows x 128 k)
    if constexpr (__is_same(XT, float)) {
        for (int idx = tid; idx < 64 * 32; idx += 256) {
            int row = idx >> 5, c4 = (idx & 31) * 4;
            int grow = r0 + row;
            float4 v = make_float4(0.f, 0.f, 0.f, 0.f);
            if (grow < N)
                v = *reinterpret_cast<const float4*>(X + (size_t)grow * 128 + c4);
            unsigned short* a = &As[row * KP + c4];
            a[0] = f2bu(v.x); a[1] = f2bu(v.y); a[2] = f2bu(v.z); a[3] = f2bu(v.w);
        }
    } else {
        for (int idx = tid; idx < 64 * 16; idx += 256) {
            int row = idx >> 4, c8 = (idx & 15) * 8;
            int grow = r0 + row;
            uint4 v = make_uint4(0u, 0u, 0u, 0u);
            if (grow < N)
                v = *reinterpret_cast<const uint4*>((const unsigned short*)X + (size_t)grow * 128 + c8);
            *reinterpret_cast<uint4*>(&As[row * KP + c8]) = v;
        }
    }
    __syncthreads();

    int w = tid >> 6, l = tid & 63, q = l >> 4, c = l & 15;
    floatx4 acc[NT];
    #pragma unroll
    for (int t = 0; t < NT; ++t) acc[t] = (floatx4){0.f, 0.f, 0.f, 0.f};

    #pragma unroll
    for (int kc = 0; kc < 4; ++kc) {
        bf16x8 a = *reinterpret_cast<const bf16x8*>(&As[(w * 16 + c) * KP + kc * 32 + q * 8]);
        #pragma unroll
        for (int t = 0; t < NT; ++t) {
            bf16x8 b = *reinterpret_cast<const bf16x8*>(&Wt[(t * 16 + c) * KP + kc * 32 + q * 8]);
            acc[t] = __builtin_amdgcn_mfma_f32_16x16x32_bf16(a, b, acc[t], 0, 0, 0);
        }
    }
    __syncthreads();
    // repack D into As ([64][M] bf16, stride KP)
    #pragma unroll
    for (int t = 0; t < NT; ++t)
        #pragma unroll
        for (int r = 0; r < 4; ++r)
            As[(w * 16 + q * 4 + r) * KP + t * 16 + c] = f2bu(acc[t][r]);
    __syncthreads();
    // coalesced bf16 store of h
    for (int idx = tid; idx < 64 * (M / 8); idx += 256) {
        int row = idx / (M / 8), g = idx % (M / 8);
        int grow = r0 + row;
        if (grow < N)
            *reinterpret_cast<uint4*>(Hout + (size_t)grow * M + g * 8) =
                *reinterpret_cast<const uint4*>(&As[row * KP + g * 8]);
    }
    // fused alpha: 4 threads per row, HPQ heads each
    {
        int r = tid >> 2, qq = tid & 3;
        int grow = r0 + r;
        if (grow < N) {
            #pragma unroll
            for (int hh = 0; hh < HPQ; ++hh) {
                int hd = qq * HPQ + hh;
                float s1 = 0.f, s2 = 0.f;
                #pragma unroll
                for (int f = 0; f < 16; f += 2) {
                    unsigned u = *reinterpret_cast<const unsigned*>(&As[r * KP + hd * 16 + f]);
                    float v0 = __uint_as_float(u << 16);
                    float v1 = __uint_as_float(u & 0xffff0000u);
                    s1 += v0 * As_s[hd * 16 + f] + v1 * As_s[hd * 16 + f + 1];
                    s2 += v0 * Ad_s[hd * 16 + f] + v1 * Ad_s[hd * 16 + f + 1];
                }
                asrc[(size_t)grow * H + hd] = s1;
                adst[(size_t)grow * H + hd] = s2;
            }
        }
    }
}

// ============== atomic-free CSR build: counting sort by dst ==================
// pairs packed u32: (dst_local << 17) | src   [src<2^17, dst_local<2^9]
#define CSR_CH 4096

__global__ __launch_bounds__(256) void csr_hist(
    const int* __restrict__ ei, int E, int DPB, int* __restrict__ histM)
{
    __shared__ int cnt[256];
    int tid = threadIdx.x;
    cnt[tid] = 0;
    __syncthreads();
    int e0 = blockIdx.x * CSR_CH;
    int e1 = min(E, e0 + CSR_CH);
    for (int e = e0 + tid; e < e1; e += 256)
        atomicAdd(&cnt[ei[E + e] / DPB], 1);
    __syncthreads();
    histM[blockIdx.x * 256 + tid] = cnt[tid];
}

__global__ __launch_bounds__(256) void csr_colscan(
    const int* __restrict__ histM, int NBLK,
    int* __restrict__ offT, int* __restrict__ btot)
{
    __shared__ int sm[512];
    int b = blockIdx.x;
    int tid = threadIdx.x;
    int i0 = tid, i1 = tid + 256;
    sm[i0] = (i0 < NBLK) ? histM[i0 * 256 + b] : 0;
    sm[i1] = (i1 < NBLK) ? histM[i1 * 256 + b] : 0;
    __syncthreads();
    #pragma unroll
    for (int o = 1; o < 512; o <<= 1) {
        int t0 = (i0 >= o) ? sm[i0 - o] : 0;
        int t1 = (i1 >= o) ? sm[i1 - o] : 0;
        __syncthreads();
        sm[i0] += t0; sm[i1] += t1;
        __syncthreads();
    }
    if (i0 < NBLK) offT[b * NBLK + i0] = (i0 == 0) ? 0 : sm[i0 - 1];
    if (i1 < NBLK) offT[b * NBLK + i1] = sm[i1 - 1];
    if (tid == 0) btot[b] = sm[511];
}

__global__ __launch_bounds__(256) void csr_basescan(
    const int* __restrict__ btot, int* __restrict__ bbase)
{
    __shared__ int sm[256];
    int tid = threadIdx.x;
    int v = btot[tid];
    sm[tid] = v;
    __syncthreads();
    #pragma unroll
    for (int o = 1; o < 256; o <<= 1) {
        int t = (tid >= o) ? sm[tid - o] : 0;
        __syncthreads();
        sm[tid] += t;
        __syncthreads();
    }
    bbase[tid] = sm[tid] - v;            // exclusive
    if (tid == 255) bbase[256] = sm[255];
}

__global__ __launch_bounds__(256) void csr_pair_scatter(
    const int* __restrict__ ei, int E, int DPB,
    const int* __restrict__ offT, int NBLK, const int* __restrict__ bbase,
    unsigned* __restrict__ pairs)
{
    __shared__ int cnt[256];
    int tid = threadIdx.x;
    int blk = blockIdx.x;
    cnt[tid] = bbase[tid] + offT[tid * NBLK + blk];
    __syncthreads();
    int e0 = blk * CSR_CH;
    int e1 = min(E, e0 + CSR_CH);
    for (int e = e0 + tid; e < e1; e += 256) {
        int s = ei[e];
        int d = ei[E + e];
        int b = d / DPB;
        int dloc = d - b * DPB;
        int pos = atomicAdd(&cnt[b], 1);
        pairs[pos] = ((unsigned)dloc << 17) | (unsigned)s;
    }
}

__global__ __launch_bounds__(256) void csr_fine(
    const unsigned* __restrict__ pairs, const int* __restrict__ bbase,
    int DPB, int N, int* __restrict__ ptr, int* __restrict__ col)
{
    __shared__ int sm[512];
    __shared__ int off[512];
    int b = blockIdx.x;
    int tid = threadIdx.x;
    int base = bbase[b];
    int tot = bbase[b + 1] - base;
    int d0 = b * DPB;
    int i0 = tid, i1 = tid + 256;
    sm[i0] = 0; sm[i1] = 0;
    __syncthreads();
    for (int i = tid; i < tot; i += 256)
        atomicAdd(&sm[pairs[base + i] >> 17], 1);
    __syncthreads();
    #pragma unroll
    for (int o = 1; o < 512; o <<= 1) {
        int t0 = (i0 >= o) ? sm[i0 - o] : 0;
        int t1 = (i1 >= o) ? sm[i1 - o] : 0;
        __syncthreads();
        sm[i0] += t0; sm[i1] += t1;
        __syncthreads();
    }
    off[i0] = base + ((i0 == 0) ? 0 : sm[i0 - 1]);
    off[i1] = base + sm[i1 - 1];
    if (i0 < DPB && d0 + i0 < N) ptr[d0 + i0] = base + sm[i0];
    if (i1 < DPB && d0 + i1 < N) ptr[d0 + i1] = base + sm[i1];
    __syncthreads();
    for (int i = tid; i < tot; i += 256) {
        unsigned p = pairs[base + i];
        int pos = atomicAdd(&off[p >> 17], 1);
        col[pos] = (int)(p & 0x1FFFFu);
    }
}

// ------- CSR agg + bias + LN + ELU fused: one WAVE per dst node -------------
// reads bf16 h, writes bf16 LN output (next GEMM re-rounds to bf16 anyway).
template<int H, int F>
__global__ __launch_bounds__(64) void agg_ln_kernel(
    const int* __restrict__ ptr, const int* __restrict__ col,
    const float* __restrict__ asrc, const float* __restrict__ adst,
    const bf16* __restrict__ hb, const float* __restrict__ bias,
    const float* __restrict__ g, const float* __restrict__ be,
    bf16* __restrict__ out, int N)
{
    constexpr int M = H * F;
    constexpr int PF = M / 64;
    int d = blockIdx.x;
    int lane = threadIdx.x;
    int f0 = lane * PF;
    int hd = f0 / F;
    int start = (d == 0) ? 0 : ptr[d - 1];
    int end = ptr[d];
    float adst_h = adst[d * H + hd];

    float ac0[PF], ac1[PF], ac2[PF], ac3[PF];
    float dn0, dn1 = 0.f, dn2 = 0.f, dn3 = 0.f;
    #pragma unroll
    for (int p = 0; p < PF; ++p) { ac1[p] = 0.f; ac2[p] = 0.f; ac3[p] = 0.f; }

    { // self loop -> chain 0
        float lg = asrc[d * H + hd] + adst_h;
        lg = lg > 0.f ? lg : 0.2f * lg;
        float w = __expf(lg);
        float v[PF];
        ldbf<PF>(hb + (size_t)d * M + f0, v);
        #pragma unroll
        for (int p = 0; p < PF; ++p) ac0[p] = w * v[p];
        dn0 = w;
    }

    int e = start;
    for (; e + 4 <= end; e += 4) {
        int s0 = col[e + 0], s1 = col[e + 1], s2 = col[e + 2], s3 = col[e + 3];
        float l0 = asrc[s0 * H + hd];
        float l1 = asrc[s1 * H + hd];
        float l2 = asrc[s2 * H + hd];
        float l3 = asrc[s3 * H + hd];
        float v0[PF], v1[PF], v2[PF], v3[PF];
        ldbf<PF>(hb + (size_t)s0 * M + f0, v0);
        ldbf<PF>(hb + (size_t)s1 * M + f0, v1);
        ldbf<PF>(hb + (size_t)s2 * M + f0, v2);
        ldbf<PF>(hb + (size_t)s3 * M + f0, v3);
        l0 += adst_h; l0 = l0 > 0.f ? l0 : 0.2f * l0; float w0 = __expf(l0);
        l1 += adst_h; l1 = l1 > 0.f ? l1 : 0.2f * l1; float w1 = __expf(l1);
        l2 += adst_h; l2 = l2 > 0.f ? l2 : 0.2f * l2; float w2 = __expf(l2);
        l3 += adst_h; l3 = l3 > 0.f ? l3 : 0.2f * l3; float w3 = __expf(l3);
        #pragma unroll
        for (int p = 0; p < PF; ++p) {
            ac0[p] += w0 * v0[p];
            ac1[p] += w1 * v1[p];
            ac2[p] += w2 * v2[p];
            ac3[p] += w3 * v3[p];
        }
        dn0 += w0; dn1 += w1; dn2 += w2; dn3 += w3;
    }
    for (; e < end; ++e) {
        int s = col[e];
        float lg = asrc[s * H + hd] + adst_h;
        lg = lg > 0.f ? lg : 0.2f * lg;
        float w = __expf(lg);
        float v[PF];
        ldbf<PF>(hb + (size_t)s * M + f0, v);
        #pragma unroll
        for (int p = 0; p < PF; ++p) ac0[p] += w * v[p];
        dn0 += w;
    }

    float den = dn0 + dn1 + dn2 + dn3;
    float rden = 1.f / (den + 1e-16f);
    float o[PF];
    float sm1 = 0.f, sm2 = 0.f;
    #pragma unroll
    for (int p = 0; p < PF; ++p) {
        o[p] = (ac0[p] + ac1[p] + ac2[p] + ac3[p]) * rden + bias[f0 + p];
        sm1 += o[p];
        sm2 += o[p] * o[p];
    }
    #pragma unroll
    for (int off = 32; off >= 1; off >>= 1) {
        sm1 += __shfl_xor(sm1, off, 64);
        sm2 += __shfl_xor(sm2, off, 64);
    }
    float mu = sm1 * (1.f / M);
    float var = sm2 * (1.f / M) - mu * mu;
    float inv = rsqrtf(var + 1e-5f);
    float y[PF];
    #pragma unroll
    for (int p = 0; p < PF; ++p) {
        float t = (o[p] - mu) * inv * g[f0 + p] + be[f0 + p];
        y[p] = t > 0.f ? t : expm1f(t);
    }
    if constexpr (PF == 2) {
        unsigned u = (unsigned)f2bu(y[0]) | ((unsigned)f2bu(y[1]) << 16);
        *reinterpret_cast<unsigned*>((unsigned short*)out + (size_t)d * M + f0) = u;
    } else {
        ((unsigned short*)out)[(size_t)d * M + f0] = f2bu(y[0]);
    }
}

// ------- layer 3 GEMM (64->10) + alpha fused: one thread per node -----------
// reads bf16 X (layer-2 LN output), writes h3 bf16 padded to 16/row.
__global__ __launch_bounds__(256) void gemm3_alpha(
    const bf16* __restrict__ X, const float* __restrict__ W3,
    const float* __restrict__ av_src, const float* __restrict__ av_dst,
    bf16* __restrict__ h3, float* __restrict__ asrc, float* __restrict__ adst,
    int N)
{
    __shared__ float Wl[640];
    int tid = threadIdx.x;
    for (int i = tid; i < 640; i += 256) Wl[i] = W3[i];
    __syncthreads();
    int n = blockIdx.x * 256 + tid;
    if (n >= N) return;
    float h[10];
    #pragma unroll
    for (int j = 0; j < 10; ++j) h[j] = 0.f;
    const unsigned short* xr = (const unsigned short*)X + (size_t)n * 64;
    for (int k2 = 0; k2 < 32; ++k2) {
        unsigned u = *reinterpret_cast<const unsigned*>(xr + k2 * 2);
        float x0 = __uint_as_float(u << 16);
        float x1 = __uint_as_float(u & 0xffff0000u);
        #pragma unroll
        for (int j = 0; j < 10; ++j)
            h[j] += x0 * Wl[(k2 * 2) * 10 + j] + x1 * Wl[(k2 * 2 + 1) * 10 + j];
    }
    float s1 = 0.f, s2 = 0.f;
    unsigned short* hr = (unsigned short*)h3 + (size_t)n * 16;
    #pragma unroll
    for (int j = 0; j < 10; j += 2) {
        unsigned u = (unsigned)f2bu(h[j]) | ((unsigned)f2bu(h[j + 1]) << 16);
        *reinterpret_cast<unsigned*>(hr + j) = u;
    }
    #pragma unroll
    for (int j = 0; j < 10; ++j) {
        s1 += h[j] * av_src[j];
        s2 += h[j] * av_dst[j];
    }
    asrc[n] = s1;
    adst[n] = s2;
}

// --- layer-3 agg + bias + log_softmax fused: one wave per dst, write d_out --
__global__ __launch_bounds__(256) void agg_l3_final(
    const int* __restrict__ ptr, const int* __restrict__ col,
    const float* __restrict__ asrc, const float* __restrict__ adst,
    const bf16* __restrict__ h, const float* __restrict__ b3,
    float* __restrict__ out, int N)
{
    int wave = threadIdx.x >> 6;
    int lane = threadIdx.x & 63;
    int d = blockIdx.x * 4 + wave;
    if (d >= N) return;
    const unsigned short* hu = (const unsigned short*)h;
    int start = (d == 0) ? 0 : ptr[d - 1];
    int end = ptr[d];
    float adst_d = adst[d];
    float lg = asrc[d] + adst_d;
    lg = lg > 0.f ? lg : 0.2f * lg;
    float w = __expf(lg);
    bool act = lane < 10;
    float a0 = act ? w * bu2f(hu[(size_t)d * 16 + lane]) : 0.f;
    float a1 = 0.f, a2 = 0.f, a3 = 0.f;
    float d0 = w, d1 = 0.f, d2 = 0.f, d3 = 0.f;
    int e = start;
    for (; e + 4 <= end; e += 4) {
        int s0 = col[e + 0], s1 = col[e + 1], s2 = col[e + 2], s3 = col[e + 3];
        float l0 = asrc[s0], l1 = asrc[s1], l2 = asrc[s2], l3 = asrc[s3];
        float v0 = act ? bu2f(hu[(size_t)s0 * 16 + lane]) : 0.f;
        float v1 = act ? bu2f(hu[(size_t)s1 * 16 + lane]) : 0.f;
        float v2 = act ? bu2f(hu[(size_t)s2 * 16 + lane]) : 0.f;
        float v3 = act ? bu2f(hu[(size_t)s3 * 16 + lane]) : 0.f;
        l0 += adst_d; l0 = l0 > 0.f ? l0 : 0.2f * l0; float w0 = __expf(l0);
        l1 += adst_d; l1 = l1 > 0.f ? l1 : 0.2f * l1; float w1 = __expf(l1);
        l2 += adst_d; l2 = l2 > 0.f ? l2 : 0.2f * l2; float w2 = __expf(l2);
        l3 += adst_d; l3 = l3 > 0.f ? l3 : 0.2f * l3; float w3 = __expf(l3);
        a0 += w0 * v0; a1 += w1 * v1; a2 += w2 * v2; a3 += w3 * v3;
        d0 += w0; d1 += w1; d2 += w2; d3 += w3;
    }
    for (; e < end; ++e) {
        int s = col[e];
        float l = asrc[s] + adst_d;
        l = l > 0.f ? l : 0.2f * l;
        float ww = __expf(l);
        if (act) a0 += ww * bu2f(hu[(size_t)s * 16 + lane]);
        d0 += ww;
    }
    float den = d0 + d1 + d2 + d3;
    float v = (a0 + a1 + a2 + a3) / (den + 1e-16f);
    float lv = act ? v + b3[lane] : -1e30f;
    float mx = lv;
    #pragma unroll
    for (int off = 1; off < 16; off <<= 1) mx = fmaxf(mx, __shfl_xor(mx, off, 16));
    float ev = act ? __expf(lv - mx) : 0.f;
    float se = ev;
    #pragma unroll
    for (int off = 1; off < 16; off <<= 1) se += __shfl_xor(se, off, 16);
    float ls = mx + logf(se);
    if (act) out[(size_t)d * 10 + lane] = lv - ls;
}

static inline int cdiv(long a, long b) { return (int)((a + b - 1) / b); }

extern "C" void kernel_launch(void* const* d_in, const int* in_sizes, int n_in,
                              void* d_out, int out_size, void* d_ws, size_t ws_size,
                              hipStream_t stream)
{
    const float* x   = (const float*)d_in[0];
    const int*   ei  = (const int*)d_in[1];
    const float* W1  = (const float*)d_in[2];
    const float* as1 = (const float*)d_in[3];
    const float* ad1 = (const float*)d_in[4];
    const float* b1  = (const float*)d_in[5];
    const float* g1  = (const float*)d_in[6];
    const float* be1 = (const float*)d_in[7];
    const float* W2  = (const float*)d_in[8];
    const float* as2 = (const float*)d_in[9];
    const float* ad2 = (const float*)d_in[10];
    const float* b2  = (const float*)d_in[11];
    const float* g2  = (const float*)d_in[12];
    const float* be2 = (const float*)d_in[13];
    const float* W3  = (const float*)d_in[14];
    const float* as3 = (const float*)d_in[15];
    const float* ad3 = (const float*)d_in[16];
    const float* b3  = (const float*)d_in[17];

    const int N = in_sizes[0] / 128;
    const int E = in_sizes[1] / 2;

    const int DPB  = cdiv(N, 256);         // dsts per bucket (<512 for u32 pack)
    const int NBLK = cdiv(E, CSR_CH);      // edge chunks (<=512)

    bf16*     hb    = (bf16*)d_ws;                      // N*128 bf16
    bf16*     aggb  = hb + (size_t)N * 128;             // N*128 bf16
    float*    asrc  = (float*)(aggb + (size_t)N * 128); // N*8
    float*    adst  = asrc + (size_t)N * 8;             // N*8
    unsigned* pairs = (unsigned*)(adst + (size_t)N * 8);// E u32
    int*      col   = (int*)(pairs + E);                // E
    int*      ptr   = col + E;                          // N+1
    int*      histM = ptr + (N + 1);                    // NBLK*256
    int*      offT  = histM + (size_t)NBLK * 256;       // 256*NBLK
    int*      btot  = offT + (size_t)NBLK * 256;        // 256
    int*      bbase = btot + 256;                       // 257
    bf16*     h3b   = hb;                               // N*16 bf16 (layer 3)

    // ---- CSR build (atomic-free counting sort; reused by all 3 layers) ----
    csr_hist<<<NBLK, 256, 0, stream>>>(ei, E, DPB, histM);
    csr_colscan<<<256, 256, 0, stream>>>(histM, NBLK, offT, btot);
    csr_basescan<<<1, 256, 0, stream>>>(btot, bbase);
    csr_pair_scatter<<<NBLK, 256, 0, stream>>>(ei, E, DPB, offT, NBLK, bbase, pairs);
    csr_fine<<<256, 256, 0, stream>>>(pairs, bbase, DPB, N, ptr, col);

    // ================= layer 1: 128 -> 8 heads x 16 =================
    gemm_mfma<float, 8><<<cdiv(N, 64), 256, 0, stream>>>(x, W1, as1, ad1, hb, asrc, adst, N);
    agg_ln_kernel<8, 16><<<N, 64, 0, stream>>>(ptr, col, asrc, adst, hb, b1, g1, be1, aggb, N);

    // ================= layer 2: 128 -> 4 heads x 16 =================
    gemm_mfma<bf16, 4><<<cdiv(N, 64), 256, 0, stream>>>(aggb, W2, as2, ad2, hb, asrc, adst, N);
    agg_ln_kernel<4, 16><<<N, 64, 0, stream>>>(ptr, col, asrc, adst, hb, b2, g2, be2, aggb, N);

    // ================= layer 3: 64 -> 1 head x 10, mean(=identity) ==
    gemm3_alpha<<<cdiv(N, 256), 256, 0, stream>>>(aggb, W3, as3, ad3, h3b, asrc, adst, N);
    agg_l3_final<<<cdiv(N, 4), 256, 0, stream>>>(ptr, col, asrc, adst, h3b, b3, (float*)d_out, N);
}

// Round 12
// 397.692 us; speedup vs baseline: 1.1728x; 1.1728x over previous
//
#include <hip/hip_runtime.h>
#include <hip/hip_bf16.h>
#include <math.h>

typedef __hip_bfloat16 bf16;
typedef __bf16 bf16x8 __attribute__((ext_vector_type(8)));
typedef float floatx4 __attribute__((ext_vector_type(4)));

__device__ __forceinline__ unsigned short f2bu(float f) {
    bf16 b = __float2bfloat16(f);
    return __builtin_bit_cast(unsigned short, b);
}
__device__ __forceinline__ float bu2f(unsigned short u) {
    return __uint_as_float(((unsigned)u) << 16);
}

// load PF bf16 features (packed) as floats
template<int PF>
__device__ __forceinline__ void ldbf(const bf16* p, float* v) {
    if constexpr (PF == 1) {
        unsigned short u = *reinterpret_cast<const unsigned short*>(p);
        v[0] = __uint_as_float(((unsigned)u) << 16);
    } else {
        unsigned u = *reinterpret_cast<const unsigned*>(p);
        v[0] = __uint_as_float(u << 16);
        v[1] = __uint_as_float(u & 0xffff0000u);
    }
}

// ====== MFMA GEMM + fused alpha: C[N,16H] = X[N,128] @ W[128,16H] ===========
// K=128 in LDS, one staging phase. Fragment layouts (m89/m91-verified):
// A[m=lane&15][k=quad*8+j], B[k=quad*8+j][n=lane&15], D[row=quad*4+reg][col=lane&15].
template<typename XT, int H>
__global__ __launch_bounds__(256) void gemm_mfma(
    const XT* __restrict__ X, const float* __restrict__ W,
    const float* __restrict__ a_src, const float* __restrict__ a_dst,
    bf16* __restrict__ Hout, float* __restrict__ asrc, float* __restrict__ adst,
    int N)
{
    constexpr int M = H * 16;
    constexpr int KP = 136;              // padded k-stride (bf16 elems)
    constexpr int NT = M / 16;           // 16-col tiles per wave
    constexpr int HPQ = H / 4;           // heads per quarter-thread
    __shared__ __align__(16) unsigned short Wt[M * KP];   // W^T: [n][k]
    __shared__ __align__(16) unsigned short As[64 * KP];  // A: [m][k]; reused for D
    __shared__ float As_s[M], Ad_s[M];
    int tid = threadIdx.x;
    int r0 = blockIdx.x * 64;

    for (int i = tid; i < M; i += 256) { As_s[i] = a_src[i]; Ad_s[i] = a_dst[i]; }
    for (int idx = tid; idx < 128 * M; idx += 256) {
        int k = idx / M, m = idx % M;
        Wt[m * KP + k] = f2bu(W[idx]);
    }
    if constexpr (__is_same(XT, float)) {
        for (int idx = tid; idx < 64 * 32; idx += 256) {
            int row = idx >> 5, c4 = (idx & 31) * 4;
            int grow = r0 + row;
            float4 v = make_float4(0.f, 0.f, 0.f, 0.f);
            if (grow < N)
                v = *reinterpret_cast<const float4*>(X + (size_t)grow * 128 + c4);
            unsigned short* a = &As[row * KP + c4];
            a[0] = f2bu(v.x); a[1] = f2bu(v.y); a[2] = f2bu(v.z); a[3] = f2bu(v.w);
        }
    } else {
        for (int idx = tid; idx < 64 * 16; idx += 256) {
            int row = idx >> 4, c8 = (idx & 15) * 8;
            int grow = r0 + row;
            uint4 v = make_uint4(0u, 0u, 0u, 0u);
            if (grow < N)
                v = *reinterpret_cast<const uint4*>((const unsigned short*)X + (size_t)grow * 128 + c8);
            *reinterpret_cast<uint4*>(&As[row * KP + c8]) = v;
        }
    }
    __syncthreads();

    int w = tid >> 6, l = tid & 63, q = l >> 4, c = l & 15;
    floatx4 acc[NT];
    #pragma unroll
    for (int t = 0; t < NT; ++t) acc[t] = (floatx4){0.f, 0.f, 0.f, 0.f};

    #pragma unroll
    for (int kc = 0; kc < 4; ++kc) {
        bf16x8 a = *reinterpret_cast<const bf16x8*>(&As[(w * 16 + c) * KP + kc * 32 + q * 8]);
        #pragma unroll
        for (int t = 0; t < NT; ++t) {
            bf16x8 b = *reinterpret_cast<const bf16x8*>(&Wt[(t * 16 + c) * KP + kc * 32 + q * 8]);
            acc[t] = __builtin_amdgcn_mfma_f32_16x16x32_bf16(a, b, acc[t], 0, 0, 0);
        }
    }
    __syncthreads();
    #pragma unroll
    for (int t = 0; t < NT; ++t)
        #pragma unroll
        for (int r = 0; r < 4; ++r)
            As[(w * 16 + q * 4 + r) * KP + t * 16 + c] = f2bu(acc[t][r]);
    __syncthreads();
    for (int idx = tid; idx < 64 * (M / 8); idx += 256) {
        int row = idx / (M / 8), g = idx % (M / 8);
        int grow = r0 + row;
        if (grow < N)
            *reinterpret_cast<uint4*>(Hout + (size_t)grow * M + g * 8) =
                *reinterpret_cast<const uint4*>(&As[row * KP + g * 8]);
    }
    {
        int r = tid >> 2, qq = tid & 3;
        int grow = r0 + r;
        if (grow < N) {
            #pragma unroll
            for (int hh = 0; hh < HPQ; ++hh) {
                int hd = qq * HPQ + hh;
                float s1 = 0.f, s2 = 0.f;
                #pragma unroll
                for (int f = 0; f < 16; f += 2) {
                    unsigned u = *reinterpret_cast<const unsigned*>(&As[r * KP + hd * 16 + f]);
                    float v0 = __uint_as_float(u << 16);
                    float v1 = __uint_as_float(u & 0xffff0000u);
                    s1 += v0 * As_s[hd * 16 + f] + v1 * As_s[hd * 16 + f + 1];
                    s2 += v0 * Ad_s[hd * 16 + f] + v1 * Ad_s[hd * 16 + f + 1];
                }
                asrc[(size_t)grow * H + hd] = s1;
                adst[(size_t)grow * H + hd] = s2;
            }
        }
    }
}

// ============== atomic-free CSR build: counting sort by dst ==================
#define CSR_CH 4096

__global__ __launch_bounds__(256) void csr_hist(
    const int* __restrict__ ei, int E, int DPB, int* __restrict__ histM)
{
    __shared__ int cnt[256];
    int tid = threadIdx.x;
    cnt[tid] = 0;
    __syncthreads();
    int e0 = blockIdx.x * CSR_CH;
    int e1 = min(E, e0 + CSR_CH);
    for (int e = e0 + tid; e < e1; e += 256)
        atomicAdd(&cnt[ei[E + e] / DPB], 1);
    __syncthreads();
    histM[blockIdx.x * 256 + tid] = cnt[tid];
}

__global__ __launch_bounds__(256) void csr_colscan(
    const int* __restrict__ histM, int NBLK,
    int* __restrict__ offT, int* __restrict__ btot)
{
    __shared__ int sm[512];
    int b = blockIdx.x;
    int tid = threadIdx.x;
    int i0 = tid, i1 = tid + 256;
    sm[i0] = (i0 < NBLK) ? histM[i0 * 256 + b] : 0;
    sm[i1] = (i1 < NBLK) ? histM[i1 * 256 + b] : 0;
    __syncthreads();
    #pragma unroll
    for (int o = 1; o < 512; o <<= 1) {
        int t0 = (i0 >= o) ? sm[i0 - o] : 0;
        int t1 = (i1 >= o) ? sm[i1 - o] : 0;
        __syncthreads();
        sm[i0] += t0; sm[i1] += t1;
        __syncthreads();
    }
    if (i0 < NBLK) offT[b * NBLK + i0] = (i0 == 0) ? 0 : sm[i0 - 1];
    if (i1 < NBLK) offT[b * NBLK + i1] = sm[i1 - 1];
    if (tid == 0) btot[b] = sm[511];
}

__global__ __launch_bounds__(256) void csr_basescan(
    const int* __restrict__ btot, int* __restrict__ bbase)
{
    __shared__ int sm[256];
    int tid = threadIdx.x;
    int v = btot[tid];
    sm[tid] = v;
    __syncthreads();
    #pragma unroll
    for (int o = 1; o < 256; o <<= 1) {
        int t = (tid >= o) ? sm[tid - o] : 0;
        __syncthreads();
        sm[tid] += t;
        __syncthreads();
    }
    bbase[tid] = sm[tid] - v;            // exclusive
    if (tid == 255) bbase[256] = sm[255];
}

__global__ __launch_bounds__(256) void csr_pair_scatter(
    const int* __restrict__ ei, int E, int DPB,
    const int* __restrict__ offT, int NBLK, const int* __restrict__ bbase,
    unsigned* __restrict__ pairs)
{
    __shared__ int cnt[256];
    int tid = threadIdx.x;
    int blk = blockIdx.x;
    cnt[tid] = bbase[tid] + offT[tid * NBLK + blk];
    __syncthreads();
    int e0 = blk * CSR_CH;
    int e1 = min(E, e0 + CSR_CH);
    for (int e = e0 + tid; e < e1; e += 256) {
        int s = ei[e];
        int d = ei[E + e];
        int b = d / DPB;
        int dloc = d - b * DPB;
        int pos = atomicAdd(&cnt[b], 1);
        pairs[pos] = ((unsigned)dloc << 17) | (unsigned)s;
    }
}

__global__ __launch_bounds__(256) void csr_fine(
    const unsigned* __restrict__ pairs, const int* __restrict__ bbase,
    int DPB, int N, int* __restrict__ ptr, int* __restrict__ col)
{
    __shared__ int sm[512];
    __shared__ int off[512];
    int b = blockIdx.x;
    int tid = threadIdx.x;
    int base = bbase[b];
    int tot = bbase[b + 1] - base;
    int d0 = b * DPB;
    int i0 = tid, i1 = tid + 256;
    sm[i0] = 0; sm[i1] = 0;
    __syncthreads();
    for (int i = tid; i < tot; i += 256)
        atomicAdd(&sm[pairs[base + i] >> 17], 1);
    __syncthreads();
    #pragma unroll
    for (int o = 1; o < 512; o <<= 1) {
        int t0 = (i0 >= o) ? sm[i0 - o] : 0;
        int t1 = (i1 >= o) ? sm[i1 - o] : 0;
        __syncthreads();
        sm[i0] += t0; sm[i1] += t1;
        __syncthreads();
    }
    off[i0] = base + ((i0 == 0) ? 0 : sm[i0 - 1]);
    off[i1] = base + sm[i1 - 1];
    if (i0 < DPB && d0 + i0 < N) ptr[d0 + i0] = base + sm[i0];
    if (i1 < DPB && d0 + i1 < N) ptr[d0 + i1] = base + sm[i1];
    __syncthreads();
    for (int i = tid; i < tot; i += 256) {
        unsigned p = pairs[base + i];
        int pos = atomicAdd(&off[p >> 17], 1);
        col[pos] = (int)(p & 0x1FFFFu);
    }
}

// ------- CSR agg + bias + LN + ELU fused: one WAVE per dst node -------------
template<int H, int F>
__global__ __launch_bounds__(64) void agg_ln_kernel(
    const int* __restrict__ ptr, const int* __restrict__ col,
    const float* __restrict__ asrc, const float* __restrict__ adst,
    const bf16* __restrict__ hb, const float* __restrict__ bias,
    const float* __restrict__ g, const float* __restrict__ be,
    bf16* __restrict__ out, int N)
{
    constexpr int M = H * F;
    constexpr int PF = M / 64;
    int d = blockIdx.x;
    int lane = threadIdx.x;
    int f0 = lane * PF;
    int hd = f0 / F;
    int start = (d == 0) ? 0 : ptr[d - 1];
    int end = ptr[d];
    float adst_h = adst[d * H + hd];

    float ac0[PF], ac1[PF], ac2[PF], ac3[PF];
    float dn0, dn1 = 0.f, dn2 = 0.f, dn3 = 0.f;
    #pragma unroll
    for (int p = 0; p < PF; ++p) { ac1[p] = 0.f; ac2[p] = 0.f; ac3[p] = 0.f; }

    {
        float lg = asrc[d * H + hd] + adst_h;
        lg = lg > 0.f ? lg : 0.2f * lg;
        float w = __expf(lg);
        float v[PF];
        ldbf<PF>(hb + (size_t)d * M + f0, v);
        #pragma unroll
        for (int p = 0; p < PF; ++p) ac0[p] = w * v[p];
        dn0 = w;
    }

    int e = start;
    for (; e + 4 <= end; e += 4) {
        int s0 = col[e + 0], s1 = col[e + 1], s2 = col[e + 2], s3 = col[e + 3];
        float l0 = asrc[s0 * H + hd];
        float l1 = asrc[s1 * H + hd];
        float l2 = asrc[s2 * H + hd];
        float l3 = asrc[s3 * H + hd];
        float v0[PF], v1[PF], v2[PF], v3[PF];
        ldbf<PF>(hb + (size_t)s0 * M + f0, v0);
        ldbf<PF>(hb + (size_t)s1 * M + f0, v1);
        ldbf<PF>(hb + (size_t)s2 * M + f0, v2);
        ldbf<PF>(hb + (size_t)s3 * M + f0, v3);
        l0 += adst_h; l0 = l0 > 0.f ? l0 : 0.2f * l0; float w0 = __expf(l0);
        l1 += adst_h; l1 = l1 > 0.f ? l1 : 0.2f * l1; float w1 = __expf(l1);
        l2 += adst_h; l2 = l2 > 0.f ? l2 : 0.2f * l2; float w2 = __expf(l2);
        l3 += adst_h; l3 = l3 > 0.f ? l3 : 0.2f * l3; float w3 = __expf(l3);
        #pragma unroll
        for (int p = 0; p < PF; ++p) {
            ac0[p] += w0 * v0[p];
            ac1[p] += w1 * v1[p];
            ac2[p] += w2 * v2[p];
            ac3[p] += w3 * v3[p];
        }
        dn0 += w0; dn1 += w1; dn2 += w2; dn3 += w3;
    }
    for (; e < end; ++e) {
        int s = col[e];
        float lg = asrc[s * H + hd] + adst_h;
        lg = lg > 0.f ? lg : 0.2f * lg;
        float w = __expf(lg);
        float v[PF];
        ldbf<PF>(hb + (size_t)s * M + f0, v);
        #pragma unroll
        for (int p = 0; p < PF; ++p) ac0[p] += w * v[p];
        dn0 += w;
    }

    float den = dn0 + dn1 + dn2 + dn3;
    float rden = 1.f / (den + 1e-16f);
    float o[PF];
    float sm1 = 0.f, sm2 = 0.f;
    #pragma unroll
    for (int p = 0; p < PF; ++p) {
        o[p] = (ac0[p] + ac1[p] + ac2[p] + ac3[p]) * rden + bias[f0 + p];
        sm1 += o[p];
        sm2 += o[p] * o[p];
    }
    #pragma unroll
    for (int off = 32; off >= 1; off >>= 1) {
        sm1 += __shfl_xor(sm1, off, 64);
        sm2 += __shfl_xor(sm2, off, 64);
    }
    float mu = sm1 * (1.f / M);
    float var = sm2 * (1.f / M) - mu * mu;
    float inv = rsqrtf(var + 1e-5f);
    float y[PF];
    #pragma unroll
    for (int p = 0; p < PF; ++p) {
        float t = (o[p] - mu) * inv * g[f0 + p] + be[f0 + p];
        y[p] = t > 0.f ? t : expm1f(t);
    }
    if constexpr (PF == 2) {
        unsigned u = (unsigned)f2bu(y[0]) | ((unsigned)f2bu(y[1]) << 16);
        *reinterpret_cast<unsigned*>((unsigned short*)out + (size_t)d * M + f0) = u;
    } else {
        ((unsigned short*)out)[(size_t)d * M + f0] = f2bu(y[0]);
    }
}

// ------- layer 3 GEMM (64->10) + alpha fused: one thread per node -----------
__global__ __launch_bounds__(256) void gemm3_alpha(
    const bf16* __restrict__ X, const float* __restrict__ W3,
    const float* __restrict__ av_src, const float* __restrict__ av_dst,
    bf16* __restrict__ h3, float* __restrict__ asrc, float* __restrict__ adst,
    int N)
{
    __shared__ float Wl[640];
    int tid = threadIdx.x;
    for (int i = tid; i < 640; i += 256) Wl[i] = W3[i];
    __syncthreads();
    int n = blockIdx.x * 256 + tid;
    if (n >= N) return;
    float h[10];
    #pragma unroll
    for (int j = 0; j < 10; ++j) h[j] = 0.f;
    const unsigned short* xr = (const unsigned short*)X + (size_t)n * 64;
    for (int k2 = 0; k2 < 32; ++k2) {
        unsigned u = *reinterpret_cast<const unsigned*>(xr + k2 * 2);
        float x0 = __uint_as_float(u << 16);
        float x1 = __uint_as_float(u & 0xffff0000u);
        #pragma unroll
        for (int j = 0; j < 10; ++j)
            h[j] += x0 * Wl[(k2 * 2) * 10 + j] + x1 * Wl[(k2 * 2 + 1) * 10 + j];
    }
    float s1 = 0.f, s2 = 0.f;
    unsigned short* hr = (unsigned short*)h3 + (size_t)n * 16;
    #pragma unroll
    for (int j = 0; j < 10; j += 2) {
        unsigned u = (unsigned)f2bu(h[j]) | ((unsigned)f2bu(h[j + 1]) << 16);
        *reinterpret_cast<unsigned*>(hr + j) = u;
    }
    #pragma unroll
    for (int j = 0; j < 10; ++j) {
        s1 += h[j] * av_src[j];
        s2 += h[j] * av_dst[j];
    }
    asrc[n] = s1;
    adst[n] = s2;
}

// --- layer-3 agg + bias + log_softmax fused: 16-lane subgroup per dst -------
// 4 dsts per wave, 16 dsts per 256-block: 4x the in-flight gathers vs
// wave-per-dst (only lanes j<10 load; softmax shuffles are width-16 segments).
__global__ __launch_bounds__(256) void agg_l3_final(
    const int* __restrict__ ptr, const int* __restrict__ col,
    const float* __restrict__ asrc, const float* __restrict__ adst,
    const bf16* __restrict__ h, const float* __restrict__ b3,
    float* __restrict__ out, int N)
{
    int tid = threadIdx.x;
    int sub16 = tid >> 4;            // 0..15 within block
    int j = tid & 15;
    int d = blockIdx.x * 16 + sub16;
    if (d >= N) return;
    const unsigned short* hu = (const unsigned short*)h;
    int start = (d == 0) ? 0 : ptr[d - 1];
    int end = ptr[d];
    float adst_d = adst[d];
    float lg = asrc[d] + adst_d;
    lg = lg > 0.f ? lg : 0.2f * lg;
    float w = __expf(lg);
    bool act = j < 10;
    float a0 = act ? w * bu2f(hu[(size_t)d * 16 + j]) : 0.f;
    float a1 = 0.f, a2 = 0.f, a3 = 0.f;
    float d0 = w, d1 = 0.f, d2 = 0.f, d3 = 0.f;
    int e = start;
    for (; e + 4 <= end; e += 4) {
        int s0 = col[e + 0], s1 = col[e + 1], s2 = col[e + 2], s3 = col[e + 3];
        float l0 = asrc[s0], l1 = asrc[s1], l2 = asrc[s2], l3 = asrc[s3];
        float v0 = act ? bu2f(hu[(size_t)s0 * 16 + j]) : 0.f;
        float v1 = act ? bu2f(hu[(size_t)s1 * 16 + j]) : 0.f;
        float v2 = act ? bu2f(hu[(size_t)s2 * 16 + j]) : 0.f;
        float v3 = act ? bu2f(hu[(size_t)s3 * 16 + j]) : 0.f;
        l0 += adst_d; l0 = l0 > 0.f ? l0 : 0.2f * l0; float w0 = __expf(l0);
        l1 += adst_d; l1 = l1 > 0.f ? l1 : 0.2f * l1; float w1 = __expf(l1);
        l2 += adst_d; l2 = l2 > 0.f ? l2 : 0.2f * l2; float w2 = __expf(l2);
        l3 += adst_d; l3 = l3 > 0.f ? l3 : 0.2f * l3; float w3 = __expf(l3);
        a0 += w0 * v0; a1 += w1 * v1; a2 += w2 * v2; a3 += w3 * v3;
        d0 += w0; d1 += w1; d2 += w2; d3 += w3;
    }
    for (; e < end; ++e) {
        int s = col[e];
        float l = asrc[s] + adst_d;
        l = l > 0.f ? l : 0.2f * l;
        float ww = __expf(l);
        if (act) a0 += ww * bu2f(hu[(size_t)s * 16 + j]);
        d0 += ww;
    }
    float den = d0 + d1 + d2 + d3;
    float v = (a0 + a1 + a2 + a3) / (den + 1e-16f);
    float lv = act ? v + b3[j] : -1e30f;
    float mx = lv;
    #pragma unroll
    for (int off = 1; off < 16; off <<= 1) mx = fmaxf(mx, __shfl_xor(mx, off, 16));
    float ev = act ? __expf(lv - mx) : 0.f;
    float se = ev;
    #pragma unroll
    for (int off = 1; off < 16; off <<= 1) se += __shfl_xor(se, off, 16);
    float ls = mx + logf(se);
    if (act) out[(size_t)d * 10 + j] = lv - ls;
}

static inline int cdiv(long a, long b) { return (int)((a + b - 1) / b); }

extern "C" void kernel_launch(void* const* d_in, const int* in_sizes, int n_in,
                              void* d_out, int out_size, void* d_ws, size_t ws_size,
                              hipStream_t stream)
{
    const float* x   = (const float*)d_in[0];
    const int*   ei  = (const int*)d_in[1];
    const float* W1  = (const float*)d_in[2];
    const float* as1 = (const float*)d_in[3];
    const float* ad1 = (const float*)d_in[4];
    const float* b1  = (const float*)d_in[5];
    const float* g1  = (const float*)d_in[6];
    const float* be1 = (const float*)d_in[7];
    const float* W2  = (const float*)d_in[8];
    const float* as2 = (const float*)d_in[9];
    const float* ad2 = (const float*)d_in[10];
    const float* b2  = (const float*)d_in[11];
    const float* g2  = (const float*)d_in[12];
    const float* be2 = (const float*)d_in[13];
    const float* W3  = (const float*)d_in[14];
    const float* as3 = (const float*)d_in[15];
    const float* ad3 = (const float*)d_in[16];
    const float* b3  = (const float*)d_in[17];

    const int N = in_sizes[0] / 128;
    const int E = in_sizes[1] / 2;

    const int DPB  = cdiv(N, 256);         // dsts per bucket (<512 for u32 pack)
    const int NBLK = cdiv(E, CSR_CH);      // edge chunks (<=512)

    bf16*     hb    = (bf16*)d_ws;                      // N*128 bf16
    bf16*     aggb  = hb + (size_t)N * 128;             // N*128 bf16
    float*    asrc  = (float*)(aggb + (size_t)N * 128); // N*8
    float*    adst  = asrc + (size_t)N * 8;             // N*8
    unsigned* pairs = (unsigned*)(adst + (size_t)N * 8);// E u32
    int*      col   = (int*)(pairs + E);                // E
    int*      ptr   = col + E;                          // N+1
    int*      histM = ptr + (N + 1);                    // NBLK*256
    int*      offT  = histM + (size_t)NBLK * 256;       // 256*NBLK
    int*      btot  = offT + (size_t)NBLK * 256;        // 256
    int*      bbase = btot + 256;                       // 257
    bf16*     h3b   = hb;                               // N*16 bf16 (layer 3)

    // ---- CSR build (atomic-free counting sort; reused by all 3 layers) ----
    csr_hist<<<NBLK, 256, 0, stream>>>(ei, E, DPB, histM);
    csr_colscan<<<256, 256, 0, stream>>>(histM, NBLK, offT, btot);
    csr_basescan<<<1, 256, 0, stream>>>(btot, bbase);
    csr_pair_scatter<<<NBLK, 256, 0, stream>>>(ei, E, DPB, offT, NBLK, bbase, pairs);
    csr_fine<<<256, 256, 0, stream>>>(pairs, bbase, DPB, N, ptr, col);

    // ================= layer 1: 128 -> 8 heads x 16 =================
    gemm_mfma<float, 8><<<cdiv(N, 64), 256, 0, stream>>>(x, W1, as1, ad1, hb, asrc, adst, N);
    agg_ln_kernel<8, 16><<<N, 64, 0, stream>>>(ptr, col, asrc, adst, hb, b1, g1, be1, aggb, N);

    // ================= layer 2: 128 -> 4 heads x 16 =================
    gemm_mfma<bf16, 4><<<cdiv(N, 64), 256, 0, stream>>>(aggb, W2, as2, ad2, hb, asrc, adst, N);
    agg_ln_kernel<4, 16><<<N, 64, 0, stream>>>(ptr, col, asrc, adst, hb, b2, g2, be2, aggb, N);

    // ================= layer 3: 64 -> 1 head x 10, mean(=identity) ==
    gemm3_alpha<<<cdiv(N, 256), 256, 0, stream>>>(aggb, W3, as3, ad3, h3b, asrc, adst, N);
    agg_l3_final<<<cdiv(N, 16), 256, 0, stream>>>(ptr, col, asrc, adst, h3b, b3, (float*)d_out, N);
}